// Round 1
// baseline (324.089 us; speedup 1.0000x reference)
//
#include <hip/hip_runtime.h>
#include <math.h>

#define NUM_GRAPHS 1024
#define NUM_FEAT 128
#define EPS 1e-5f
#define ROWS_PER_BLOCK 512

// ws layout (floats): [0,1024) gsum | [1024,2048) gss | [2048,3072) gcnt(int) |
//                     [3072,4096) gmean | [4096,5120) ginv_std
__global__ void zero_ws_kernel(float* ws) {
    int i = blockIdx.x * blockDim.x + threadIdx.x;
    if (i < 3 * NUM_GRAPHS) ws[i] = 0.0f;  // zero bits also zero the int counts
}

__global__ void pass1_kernel(const float* __restrict__ x,
                             const int* __restrict__ batch,
                             float* __restrict__ gsum,
                             float* __restrict__ gss,
                             int* __restrict__ gcnt,
                             int n_rows) {
    __shared__ float lsum[NUM_GRAPHS];
    __shared__ float lss[NUM_GRAPHS];
    __shared__ int   lcnt[NUM_GRAPHS];

    int r0 = blockIdx.x * ROWS_PER_BLOCK;
    if (r0 >= n_rows) return;
    int r1 = min(r0 + ROWS_PER_BLOCK, n_rows);

    // batch is sorted: this block touches only graphs in [g_lo, g_hi]
    int g_lo = batch[r0];
    int g_hi = batch[r1 - 1];

    for (int g = g_lo + (int)threadIdx.x; g <= g_hi; g += blockDim.x) {
        lsum[g] = 0.0f; lss[g] = 0.0f; lcnt[g] = 0;
    }
    __syncthreads();

    const int lane32  = threadIdx.x & 31;   // 32 lanes per row (128 floats = 32 float4)
    const int rowgrp  = threadIdx.x >> 5;   // 0..7
    const int nrowgrp = blockDim.x >> 5;    // 8

    for (int r = r0 + rowgrp; r < r1; r += nrowgrp) {
        const float4* xr = reinterpret_cast<const float4*>(x + (size_t)r * NUM_FEAT);
        float4 v = xr[lane32];
        float s  = v.x + v.y + v.z + v.w;
        float ss = v.x * v.x + v.y * v.y + v.z * v.z + v.w * v.w;
        #pragma unroll
        for (int off = 16; off > 0; off >>= 1) {
            s  += __shfl_down(s,  off, 32);
            ss += __shfl_down(ss, off, 32);
        }
        if (lane32 == 0) {
            int g = batch[r];
            atomicAdd(&lsum[g], s);
            atomicAdd(&lss[g],  ss);
            atomicAdd(&lcnt[g], 1);
        }
    }
    __syncthreads();

    for (int g = g_lo + (int)threadIdx.x; g <= g_hi; g += blockDim.x) {
        if (lcnt[g] > 0) {
            atomicAdd(&gsum[g], lsum[g]);
            atomicAdd(&gss[g],  lss[g]);
            atomicAdd(&gcnt[g], lcnt[g]);
        }
    }
}

__global__ void stats_kernel(const float* __restrict__ gsum,
                             const float* __restrict__ gss,
                             const int* __restrict__ gcnt,
                             float* __restrict__ gmean,
                             float* __restrict__ ginv) {
    int g = blockIdx.x * blockDim.x + threadIdx.x;
    if (g >= NUM_GRAPHS) return;
    float denom = fmaxf((float)gcnt[g] * (float)NUM_FEAT, 1.0f);
    float mean = gsum[g] / denom;
    float var  = gss[g] / denom - mean * mean;
    var = fmaxf(var, 0.0f);
    gmean[g] = mean;
    ginv[g]  = rsqrtf(var + EPS);
}

__global__ void pass2_kernel(const float* __restrict__ x,
                             const int* __restrict__ batch,
                             const float* __restrict__ weight,
                             const float* __restrict__ bias,
                             const float* __restrict__ gmean,
                             const float* __restrict__ ginv,
                             float* __restrict__ out,
                             int n_rows) {
    const size_t total4 = (size_t)n_rows * (NUM_FEAT / 4);  // 32 float4 per row
    size_t i = (size_t)blockIdx.x * blockDim.x + threadIdx.x;
    const size_t stride = (size_t)gridDim.x * blockDim.x;
    const float4* x4 = reinterpret_cast<const float4*>(x);
    const float4* w4 = reinterpret_cast<const float4*>(weight);
    const float4* b4 = reinterpret_cast<const float4*>(bias);
    float4* o4 = reinterpret_cast<float4*>(out);

    for (; i < total4; i += stride) {
        int row = (int)(i >> 5);
        int c4  = (int)(i & 31);
        int g = batch[row];
        float mean = gmean[g];
        float inv  = ginv[g];
        float4 v = x4[i];
        float4 w = w4[c4];
        float4 b = b4[c4];
        float4 o;
        o.x = w.x * ((v.x - mean) * inv) + b.x;
        o.y = w.y * ((v.y - mean) * inv) + b.y;
        o.z = w.z * ((v.z - mean) * inv) + b.z;
        o.w = w.w * ((v.w - mean) * inv) + b.w;
        o4[i] = o;
    }
}

extern "C" void kernel_launch(void* const* d_in, const int* in_sizes, int n_in,
                              void* d_out, int out_size, void* d_ws, size_t ws_size,
                              hipStream_t stream) {
    const float* x      = (const float*)d_in[0];
    const int*   batch  = (const int*)d_in[1];
    const float* weight = (const float*)d_in[2];
    const float* bias   = (const float*)d_in[3];
    float* out = (float*)d_out;

    const int n_rows = in_sizes[1];  // NUM_NODES

    float* ws    = (float*)d_ws;
    float* gsum  = ws;
    float* gss   = ws + NUM_GRAPHS;
    int*   gcnt  = (int*)(ws + 2 * NUM_GRAPHS);
    float* gmean = ws + 3 * NUM_GRAPHS;
    float* ginv  = ws + 4 * NUM_GRAPHS;

    // zero accumulators (harness poisons ws once; we must re-zero every call)
    zero_ws_kernel<<<(3 * NUM_GRAPHS + 255) / 256, 256, 0, stream>>>(ws);

    int p1_blocks = (n_rows + ROWS_PER_BLOCK - 1) / ROWS_PER_BLOCK;
    pass1_kernel<<<p1_blocks, 256, 0, stream>>>(x, batch, gsum, gss, gcnt, n_rows);

    stats_kernel<<<(NUM_GRAPHS + 255) / 256, 256, 0, stream>>>(gsum, gss, gcnt, gmean, ginv);

    size_t total4 = (size_t)n_rows * (NUM_FEAT / 4);
    int p2_blocks = 2048;
    (void)total4;
    pass2_kernel<<<p2_blocks, 256, 0, stream>>>(x, batch, weight, bias, gmean, ginv, out, n_rows);
}

// Round 2
// 282.982 us; speedup vs baseline: 1.1453x; 1.1453x over previous
//
#include <hip/hip_runtime.h>
#include <math.h>

#define NUM_GRAPHS 1024
#define NUM_FEAT 128
#define EPS 1e-5f
#define ROWS_PER_BLOCK 512

typedef float f4 __attribute__((ext_vector_type(4)));

// ws layout (floats): [0,1024) gsum | [1024,2048) gss | [2048,3072) gcnt(int) |
//                     [3072,4096) gmean | [4096,5120) ginv_std
__global__ void zero_ws_kernel(float* ws) {
    int i = blockIdx.x * blockDim.x + threadIdx.x;
    if (i < 3 * NUM_GRAPHS) ws[i] = 0.0f;  // zero bits also zero the int counts
}

__global__ void pass1_kernel(const float* __restrict__ x,
                             const int* __restrict__ batch,
                             float* __restrict__ gsum,
                             float* __restrict__ gss,
                             int* __restrict__ gcnt,
                             int n_rows) {
    int r0 = blockIdx.x * ROWS_PER_BLOCK;
    if (r0 >= n_rows) return;
    int r1 = min(r0 + ROWS_PER_BLOCK, n_rows);

    const int lane32  = threadIdx.x & 31;   // 32 lanes per row (128 floats = 32 float4)
    const int rowgrp  = threadIdx.x >> 5;   // 0..7
    const int nrowgrp = blockDim.x >> 5;    // 8

    // batch is sorted: accumulate in registers until the graph id changes,
    // then flush once (shfl reduce + 3 global atomics). ~2 flushes per group.
    float s = 0.0f, ss = 0.0f;
    int cnt = 0, cur_g = -1;

    for (int r = r0 + rowgrp; r < r1; r += nrowgrp) {
        int g = batch[r];  // uniform across the 32-lane group (broadcast load)
        if (g != cur_g) {
            if (cnt > 0) {
                float ts = s, tss = ss;
                #pragma unroll
                for (int off = 16; off > 0; off >>= 1) {
                    ts  += __shfl_down(ts,  off, 32);
                    tss += __shfl_down(tss, off, 32);
                }
                if (lane32 == 0) {
                    atomicAdd(&gsum[cur_g], ts);
                    atomicAdd(&gss[cur_g],  tss);
                    atomicAdd(&gcnt[cur_g], cnt);
                }
            }
            s = 0.0f; ss = 0.0f; cnt = 0; cur_g = g;
        }
        const f4 v = reinterpret_cast<const f4*>(x + (size_t)r * NUM_FEAT)[lane32];
        s += v.x + v.y + v.z + v.w;
        ss = fmaf(v.x, v.x, fmaf(v.y, v.y, fmaf(v.z, v.z, fmaf(v.w, v.w, ss))));
        cnt += 1;
    }
    if (cnt > 0) {
        float ts = s, tss = ss;
        #pragma unroll
        for (int off = 16; off > 0; off >>= 1) {
            ts  += __shfl_down(ts,  off, 32);
            tss += __shfl_down(tss, off, 32);
        }
        if (lane32 == 0) {
            atomicAdd(&gsum[cur_g], ts);
            atomicAdd(&gss[cur_g],  tss);
            atomicAdd(&gcnt[cur_g], cnt);
        }
    }
}

__global__ void stats_kernel(const float* __restrict__ gsum,
                             const float* __restrict__ gss,
                             const int* __restrict__ gcnt,
                             float* __restrict__ gmean,
                             float* __restrict__ ginv) {
    int g = blockIdx.x * blockDim.x + threadIdx.x;
    if (g >= NUM_GRAPHS) return;
    float denom = fmaxf((float)gcnt[g] * (float)NUM_FEAT, 1.0f);
    float mean = gsum[g] / denom;
    float var  = gss[g] / denom - mean * mean;
    var = fmaxf(var, 0.0f);
    gmean[g] = mean;
    ginv[g]  = rsqrtf(var + EPS);
}

// Reverse-order sweep: pass1 left the TAIL of x resident in the 256 MB L3,
// so read tail-first. Nontemporal stores keep `out` from evicting x.
__global__ void pass2_kernel(const float* __restrict__ x,
                             const int* __restrict__ batch,
                             const float* __restrict__ weight,
                             const float* __restrict__ bias,
                             const float* __restrict__ gmean,
                             const float* __restrict__ ginv,
                             float* __restrict__ out,
                             int n_rows) {
    const long long total4 = (long long)n_rows * (NUM_FEAT / 4);  // 32 f4 per row
    const long long stride = (long long)gridDim.x * blockDim.x;
    const long long tid    = (long long)blockIdx.x * blockDim.x + threadIdx.x;
    const long long nIter  = (total4 + stride - 1) / stride;

    const f4* x4 = reinterpret_cast<const f4*>(x);
    const f4* w4 = reinterpret_cast<const f4*>(weight);
    const f4* b4 = reinterpret_cast<const f4*>(bias);
    f4* o4 = reinterpret_cast<f4*>(out);

    for (long long k = nIter - 1; k >= 0; --k) {
        long long i = k * stride + tid;
        if (i >= total4) continue;
        int row = (int)(i >> 5);
        int c4  = (int)(i & 31);
        int g = batch[row];
        float mean = gmean[g];
        float inv  = ginv[g];
        f4 v = x4[i];
        f4 w = w4[c4];
        f4 b = b4[c4];
        f4 o;
        o.x = fmaf(w.x, (v.x - mean) * inv, b.x);
        o.y = fmaf(w.y, (v.y - mean) * inv, b.y);
        o.z = fmaf(w.z, (v.z - mean) * inv, b.z);
        o.w = fmaf(w.w, (v.w - mean) * inv, b.w);
        __builtin_nontemporal_store(o, &o4[i]);
    }
}

extern "C" void kernel_launch(void* const* d_in, const int* in_sizes, int n_in,
                              void* d_out, int out_size, void* d_ws, size_t ws_size,
                              hipStream_t stream) {
    const float* x      = (const float*)d_in[0];
    const int*   batch  = (const int*)d_in[1];
    const float* weight = (const float*)d_in[2];
    const float* bias   = (const float*)d_in[3];
    float* out = (float*)d_out;

    const int n_rows = in_sizes[1];  // NUM_NODES

    float* ws    = (float*)d_ws;
    float* gsum  = ws;
    float* gss   = ws + NUM_GRAPHS;
    int*   gcnt  = (int*)(ws + 2 * NUM_GRAPHS);
    float* gmean = ws + 3 * NUM_GRAPHS;
    float* ginv  = ws + 4 * NUM_GRAPHS;

    // zero accumulators (harness poisons ws once; we must re-zero every call)
    zero_ws_kernel<<<(3 * NUM_GRAPHS + 255) / 256, 256, 0, stream>>>(ws);

    int p1_blocks = (n_rows + ROWS_PER_BLOCK - 1) / ROWS_PER_BLOCK;
    pass1_kernel<<<p1_blocks, 256, 0, stream>>>(x, batch, gsum, gss, gcnt, n_rows);

    stats_kernel<<<(NUM_GRAPHS + 255) / 256, 256, 0, stream>>>(gsum, gss, gcnt, gmean, ginv);

    pass2_kernel<<<2048, 256, 0, stream>>>(x, batch, weight, bias, gmean, ginv, out, n_rows);
}